// Round 11
// baseline (583.611 us; speedup 1.0000x reference)
//
#include <hip/hip_runtime.h>
#include <stdint.h>
#include <stddef.h>

typedef __bf16 bf16_t;
typedef __bf16 bf16x4 __attribute__((ext_vector_type(4)));
typedef __bf16 bf16x8 __attribute__((ext_vector_type(8)));
typedef float  f32x4  __attribute__((ext_vector_type(4)));
typedef float  f32x16 __attribute__((ext_vector_type(16)));

#define H_   12
#define N_   49
#define C_   384
#define D_   32
#define NW_  64
#define C3_  1152

// ---- LDS layout (bytes) ----
// xs: 49 x 388 bf16 (38024 B) — shared x tile (stride 388: bank step 2 ->
//     2-way-free for 32-lane b128 reads).
// 12 per-wave arenas (10376 B each): private to wave h = head h.
//   bytes 0..3331   : q  [49][34] (stride 34: bank step 17, odd -> conflict-free)
//   bytes 3332..6663: k  [49][34]
//   bytes 6664..10375: vT [32][58] (stride 58: bank step 29, odd -> free);
//                      cols 48..57 zeroed (PV b128 reads x P==0)
// After qf/kf hoists (P3 start) the arena is repurposed:
//   ao [49][40] bytes 0..3919 (q + first 588 B of k) — P4-conflict-free
//   P  16x72 elems bytes 3920..6223 (inside k region, disjoint from ao)
// +16 B tail guard (last arena's vT b128 overrun).
#define XS_STRIDE 388
#define ARENA_OFF 38024
#define ARENA_SZ  10376
#define AQ_STRIDE 34
#define AK_OFF    3332
#define AV_OFF    6664
#define AV_STRIDE 58
#define AO_STRIDE 40
#define P_OFF     1960           // elems from aq (byte 3920)
#define P_STRIDE  72
#define SMEM_BYTES 162552        // 38024 + 12*10376 + 16  (<= 163840)

#define WQKV_ELEMS  (C3_ * C_)   // 442368 (same size, new fragment order)
#define WPROJ_ELEMS (C_ * C_)    // 147456

// P4 row clamp (16x16 path): tile mi==3 covers toks 48..63 -> clamp 48.
#define XF_ROW(mi) ((mi) == 3 ? 48 : (mi) * 16 + l15)

// ---------------------------------------------------------------------------
// prep_all:
//  blocks 0..863   : wqkvT in 32x32x16 A/B fragment order:
//    wqkvT[((tile*24+ks)*64+lane)*8 + j] = W[ks*16+(lane>>5)*8+j][tile*32+(lane&31)]
//  blocks 864..935 : wprojT in 16x16x32 fragment order (unchanged path)
//  blocks 936..1703: btbl[w][h][m][n] = (rpb+mask)*log2e, n padded to 64
// ---------------------------------------------------------------------------
__global__ void prep_all(const float* __restrict__ qkv_w,
                         const float* __restrict__ proj_w,
                         const float* __restrict__ mask,
                         const float* __restrict__ rpb,
                         bf16_t* __restrict__ wqkvT,
                         bf16_t* __restrict__ wprojT,
                         bf16_t* __restrict__ btbl)
{
    __shared__ bf16_t tl[32][72];
    int bid = blockIdx.x;
    const int t = threadIdx.x;
    if (bid < 864) {
        const int tile = bid / 24, ks = bid % 24;
        // load 16 k-rows x 32 chans
        {
            int idx = t;              // 0..255 -> rows 0..7
            int row = idx >> 5, col = idx & 31;
            tl[row][col] = (bf16_t)qkv_w[(ks * 16 + row) * C3_ + tile * 32 + col];
            idx = t + 256;            // rows 8..15
            row = idx >> 5; col = idx & 31;
            tl[row][col] = (bf16_t)qkv_w[(ks * 16 + row) * C3_ + tile * 32 + col];
        }
        __syncthreads();
        const int lane = t & 63, grp = t >> 6;
        const int l31 = lane & 31, q5 = lane >> 5;
        bf16_t v0 = tl[q5 * 8 + grp * 2][l31];
        bf16_t v1 = tl[q5 * 8 + grp * 2 + 1][l31];
        bf16_t* dst = wqkvT + ((size_t)(tile * 24 + ks) * 64 + lane) * 8 + grp * 2;
        dst[0] = v0; dst[1] = v1;
    } else if (bid < 936) {
        bid -= 864;
        const int ks = bid % 12, g = bid / 12;
        const int n0 = g * 64;
        const int r0 = t >> 6, cc = t & 63;
        #pragma unroll
        for (int p = 0; p < 8; ++p) {
            int row = p * 4 + r0;
            tl[row][cc] = (bf16_t)proj_w[(ks * 32 + row) * C_ + n0 + cc];
        }
        __syncthreads();
        const int lane = t & 63, ctl = t >> 6;
        const int q4 = lane >> 4, l15 = lane & 15;
        bf16x8 v;
        #pragma unroll
        for (int j = 0; j < 8; ++j) v[j] = tl[q4 * 8 + j][ctl * 16 + l15];
        *(bf16x8*)(wprojT + ((size_t)((g * 4 + ctl) * 12 + ks) * 64 + lane) * 8) = v;
    } else {
        bid -= 936;
        const int w = bid / H_, h = bid % H_;
        bf16_t* out = btbl + (size_t)(w * H_ + h) * (N_ * 64);
        for (int idx = t; idx < N_ * 64; idx += 256) {
            int m = idx >> 6, n = idx & 63;
            float v = 0.f;
            if (n < N_)
                v = (rpb[(h * N_ + m) * N_ + n] + mask[((size_t)w * N_ + m) * N_ + n])
                    * 1.4426950408889634f;
            out[idx] = (bf16_t)v;
        }
    }
}

// ---------------------------------------------------------------------------
// Head-decoupled fused kernel: one block per window, 12 waves = 12 heads.
// This round: P2 uses 32x32x16 MFMA, single pass (6 f32x16 accumulators):
//   - MFMA instrs 288->144/wave at +20% FLOP/cyc
//   - xf LDS traffic HALVED (48 b128 vs 96) -- LDS was the most-loaded pipe
//   - epilogue writes conflict-free (strides 34/58)
// P3 (attention) and P4 (proj) keep the proven 16x16x32 structure.
// Barriers: B0 (xs staged) and B1 (all ao ready) only.
// ---------------------------------------------------------------------------
__global__ __launch_bounds__(768, 3)
void fused_window_attn(const float* __restrict__ x,
                       const float* __restrict__ qkv_b,
                       const float* __restrict__ proj_b,
                       const bf16_t* __restrict__ wqkvT,
                       const bf16_t* __restrict__ wprojT,
                       const bf16_t* __restrict__ btbl,
                       float* __restrict__ out)
{
    __shared__ __align__(16) unsigned char smem[SMEM_BYTES];
    bf16_t* xs = (bf16_t*)smem;

    const int tid  = threadIdx.x;
    const int wave = tid >> 6;                  // 0..11 = head
    const int lane = tid & 63;
    const int q4   = lane >> 4;
    const int l15  = lane & 15;
    const int l31  = lane & 31;
    const int q5   = lane >> 5;
    const int b    = blockIdx.x;

    bf16_t* aq = (bf16_t*)(smem + ARENA_OFF + wave * ARENA_SZ);          // q, then ao
    bf16_t* ak = (bf16_t*)(smem + ARENA_OFF + wave * ARENA_SZ + AK_OFF); // k, then P
    bf16_t* av = (bf16_t*)(smem + ARENA_OFF + wave * ARENA_SZ + AV_OFF); // vT

    const f32x4 z4 = {0.f, 0.f, 0.f, 0.f};

    // ---------------- P1: zero own vT pad cols; stage x -> xs -------------
    {
        // vT cols 48..57 zeroed (P columns n>=49 are exact zeros, but vf
        // b128 reads touch these bytes: 0*NaN = NaN -> need finite).
        for (int t2 = lane; t2 < 320; t2 += 64) {
            int r = t2 / 10, c = t2 - r * 10;
            av[r * AV_STRIDE + 48 + c] = (bf16_t)0.f;
        }
        if (tid < 8) ((bf16_t*)(smem + SMEM_BYTES - 16))[tid] = (bf16_t)0.f;

        const float* xg = x + (size_t)b * (N_ * C_);
        for (int t2 = tid; t2 < (N_ * C_) / 4; t2 += 768) {
            float4 v = ((const float4*)xg)[t2];
            int r = t2 / 96, c4 = t2 % 96;
            bf16x4 o;
            o[0] = (bf16_t)v.x; o[1] = (bf16_t)v.y;
            o[2] = (bf16_t)v.z; o[3] = (bf16_t)v.w;
            *(bf16x4*)(xs + r * XS_STRIDE + c4 * 4) = o;
        }
    }
    __syncthreads();   // B0: xs ready for all waves

    // ---------------- P2: qkv GEMM, 32x32x16, single pass -----------------
    // Wave h owns 3 chan-tiles of 32 (q, k, v of head h) x 2 tok-tiles.
    // A-type (q,k): D = mfma(W, X) -> D[chan][tok]; B-type (v): D = mfma(X, W).
    {
        f32x16 aQ0 = {0.f,0.f,0.f,0.f,0.f,0.f,0.f,0.f,0.f,0.f,0.f,0.f,0.f,0.f,0.f,0.f};
        f32x16 aQ1 = aQ0, aK0 = aQ0, aK1 = aQ0, aV0 = aQ0, aV1 = aQ0;

        const int xr1 = (l31 < 17) ? 32 + l31 : 48;   // tok-tile 1 clamp
        const bf16_t* wbq = wqkvT + ((size_t)((wave)      * 24) * 64 + lane) * 8;
        const bf16_t* wbk = wqkvT + ((size_t)((12 + wave) * 24) * 64 + lane) * 8;
        const bf16_t* wbv = wqkvT + ((size_t)((24 + wave) * 24) * 64 + lane) * 8;

        bf16x8 wq = *(const bf16x8*)(wbq);
        bf16x8 wk = *(const bf16x8*)(wbk);
        bf16x8 wv = *(const bf16x8*)(wbv);
        bf16x8 x0 = *(const bf16x8*)(xs + l31 * XS_STRIDE + q5 * 8);
        bf16x8 x1 = *(const bf16x8*)(xs + xr1 * XS_STRIDE + q5 * 8);

        #pragma unroll
        for (int ks = 0; ks < 24; ++ks) {
            bf16x8 wqn, wkn, wvn, x0n, x1n;
            if (ks < 23) {
                wqn = *(const bf16x8*)(wbq + (ks + 1) * 512);
                wkn = *(const bf16x8*)(wbk + (ks + 1) * 512);
                wvn = *(const bf16x8*)(wbv + (ks + 1) * 512);
                x0n = *(const bf16x8*)(xs + l31 * XS_STRIDE + (ks + 1) * 16 + q5 * 8);
                x1n = *(const bf16x8*)(xs + xr1 * XS_STRIDE + (ks + 1) * 16 + q5 * 8);
            }
            aQ0 = __builtin_amdgcn_mfma_f32_32x32x16_bf16(wq, x0, aQ0, 0, 0, 0);
            aQ1 = __builtin_amdgcn_mfma_f32_32x32x16_bf16(wq, x1, aQ1, 0, 0, 0);
            aK0 = __builtin_amdgcn_mfma_f32_32x32x16_bf16(wk, x0, aK0, 0, 0, 0);
            aK1 = __builtin_amdgcn_mfma_f32_32x32x16_bf16(wk, x1, aK1, 0, 0, 0);
            aV0 = __builtin_amdgcn_mfma_f32_32x32x16_bf16(x0, wv, aV0, 0, 0, 0);
            aV1 = __builtin_amdgcn_mfma_f32_32x32x16_bf16(x1, wv, aV1, 0, 0, 0);
            if (ks < 23) { wq = wqn; wk = wkn; wv = wvn; x0 = x0n; x1 = x1n; }
        }

        // ---- epilogue Q/K (A-type): col=lane&31=tok, chan=(r&3)+8(r>>2)+4q5
        #pragma unroll
        for (int a = 0; a < 4; ++a) {
            const int c0 = 8 * a + 4 * q5;
            float4 bq = *(const float4*)(qkv_b + wave * 32 + c0);
            float4 bk = *(const float4*)(qkv_b + C_ + wave * 32 + c0);
            const float* bqp = (const float*)&bq;
            const float* bkp = (const float*)&bk;
            bf16x4 oq, ok;
            #pragma unroll
            for (int r = 0; r < 4; ++r) {
                oq[r] = (bf16_t)(aQ0[4 * a + r] + bqp[r]);
                ok[r] = (bf16_t)(aK0[4 * a + r] + bkp[r]);
            }
            *(bf16x4*)(aq + l31 * AQ_STRIDE + c0) = oq;
            *(bf16x4*)(ak + l31 * AQ_STRIDE + c0) = ok;
            if (l31 < 17) {           // tok-tile 1: toks 32..48
                bf16x4 oq1, ok1;
                #pragma unroll
                for (int r = 0; r < 4; ++r) {
                    oq1[r] = (bf16_t)(aQ1[4 * a + r] + bqp[r]);
                    ok1[r] = (bf16_t)(aK1[4 * a + r] + bkp[r]);
                }
                *(bf16x4*)(aq + (32 + l31) * AQ_STRIDE + c0) = oq1;
                *(bf16x4*)(ak + (32 + l31) * AQ_STRIDE + c0) = ok1;
            }
        }
        // ---- epilogue V (B-type): col=lane&31=dim, tok=(r&3)+8(r>>2)+4q5
        {
            const float bb = qkv_b[2 * C_ + wave * 32 + l31];
            #pragma unroll
            for (int tt = 0; tt < 2; ++tt) {
                #pragma unroll
                for (int a = 0; a < 4; ++a) {
                    const int t0 = tt * 32 + 8 * a + 4 * q5;
                    if (t0 + 3 < N_) {
                        bf16x4 o;
                        #pragma unroll
                        for (int r = 0; r < 4; ++r)
                            o[r] = (bf16_t)((tt ? aV1[4 * a + r] : aV0[4 * a + r]) + bb);
                        *(bf16x4*)(av + l31 * AV_STRIDE + t0) = o;
                    } else {
                        #pragma unroll
                        for (int r = 0; r < 4; ++r)
                            if (t0 + r < N_)
                                av[l31 * AV_STRIDE + t0 + r] =
                                    (bf16_t)((tt ? aV1[4 * a + r] : aV0[4 * a + r]) + bb);
                    }
                }
            }
        }
    }
    // NO barrier: wave h's arena is complete; proceed straight to attention.

    // ---------------- P3: attention for head h (16x16x32, private arena) --
    {
        bf16_t* pb = aq + P_OFF;   // P at arena byte 3920 (disjoint from ao)
        const bf16_t* tb = btbl + (size_t)((b & (NW_ - 1)) * H_ + wave) * (N_ * 64);
        const float SC = 0.17677669529663687f * 1.4426950408889634f;

        bf16x8 kf[4];
        #pragma unroll
        for (int ni = 0; ni < 4; ++ni) {
            const int kr = (ni == 3) ? 48 : ni * 16 + l15;
            kf[ni] = *(const bf16x8*)(ak + kr * AQ_STRIDE + q4 * 8);
        }
        bf16x8 vf[2][2];
        #pragma unroll
        for (int ks2 = 0; ks2 < 2; ++ks2)
            #pragma unroll
            for (int dt = 0; dt < 2; ++dt)
                vf[ks2][dt] = *(const bf16x8*)(av + (dt * 16 + l15) * AV_STRIDE
                                                  + ks2 * 32 + q4 * 8);
        bf16x8 qf[4];
        #pragma unroll
        for (int mt = 0; mt < 4; ++mt) {
            const int qr = (mt == 3) ? 48 : mt * 16 + l15;
            qf[mt] = *(const bf16x8*)(aq + qr * AQ_STRIDE + q4 * 8);
        }
        // q and k fully hoisted; arena repurposed: ao (stride 40) + P.

        #pragma unroll
        for (int mt = 0; mt < 4; ++mt) {
            f32x4 sacc[4];
            #pragma unroll
            for (int ni = 0; ni < 4; ++ni)
                sacc[ni] = __builtin_amdgcn_mfma_f32_16x16x32_bf16(
                    kf[ni], qf[mt], z4, 0, 0, 0);

            const int m  = mt * 16 + l15;
            const int mc = m < 48 ? m : 48;
            float den = 0.f;
            #pragma unroll
            for (int ni = 0; ni < 4; ++ni) {
                bf16x4 bv = *(const bf16x4*)(tb + (size_t)mc * 64 + ni * 16 + q4 * 4);
                #pragma unroll
                for (int r = 0; r < 4; ++r) {
                    const int n = ni * 16 + q4 * 4 + r;
                    float s = 0.f;
                    if (n < N_)
                        s = __builtin_exp2f(sacc[ni][r] * SC + (float)bv[r]);
                    sacc[ni][r] = s;
                    den += s;
                }
            }
            den += __shfl_xor(den, 16);
            den += __shfl_xor(den, 32);
            const float ri = __builtin_amdgcn_rcpf(den);

            // P write (exact zeros for n>=49; rows m>=49 skipped -> stale,
            // masked at ao staging)
            if (m < N_) {
                #pragma unroll
                for (int ni = 0; ni < 4; ++ni) {
                    bf16x4 o;
                    #pragma unroll
                    for (int r = 0; r < 4; ++r) o[r] = (bf16_t)(sacc[ni][r] * ri);
                    *(bf16x4*)(pb + l15 * P_STRIDE + ni * 16 + q4 * 4) = o;
                }
            }

            f32x4 o0 = z4, o1 = z4;
            #pragma unroll
            for (int ks2 = 0; ks2 < 2; ++ks2) {
                bf16x8 pf = *(const bf16x8*)(pb + l15 * P_STRIDE + ks2 * 32 + q4 * 8);
                o0 = __builtin_amdgcn_mfma_f32_16x16x32_bf16(pf, vf[ks2][0], o0, 0, 0, 0);
                o1 = __builtin_amdgcn_mfma_f32_16x16x32_bf16(pf, vf[ks2][1], o1, 0, 0, 0);
            }
            #pragma unroll
            for (int r = 0; r < 4; ++r) {
                const int ms = mt * 16 + q4 * 4 + r;
                if (ms < N_) {
                    aq[ms * AO_STRIDE + l15]      = (bf16_t)o0[r];
                    aq[ms * AO_STRIDE + 16 + l15] = (bf16_t)o1[r];
                }
            }
        }
    }
    __syncthreads();   // B1: all heads' ao staged in arenas

    // ---------------- P4: out = ao @ Wproj + b, 16x16x32, 2 tiles/wave ----
    {
        f32x4 pacc[2][4];
        #pragma unroll
        for (int jj = 0; jj < 2; ++jj)
            #pragma unroll
            for (int mi = 0; mi < 4; ++mi) pacc[jj][mi] = z4;

        bf16x8 w0[2], w1[2], w2[2], afc[4], afn[4];
        #pragma unroll
        for (int jj = 0; jj < 2; ++jj) {
            w0[jj] = *(const bf16x8*)(wprojT +
                ((size_t)((wave * 2 + jj) * 12 + 0) * 64 + lane) * 8);
            w1[jj] = *(const bf16x8*)(wprojT +
                ((size_t)((wave * 2 + jj) * 12 + 1) * 64 + lane) * 8);
        }
        #pragma unroll
        for (int mi = 0; mi < 4; ++mi)
            afc[mi] = *(const bf16x8*)((bf16_t*)(smem + ARENA_OFF)
                                       + XF_ROW(mi) * AO_STRIDE + q4 * 8);

        #pragma unroll
        for (int ks = 0; ks < 12; ++ks) {
            if (ks < 10) {
                #pragma unroll
                for (int jj = 0; jj < 2; ++jj)
                    w2[jj] = *(const bf16x8*)(wprojT +
                        ((size_t)((wave * 2 + jj) * 12 + ks + 2) * 64 + lane) * 8);
            }
            if (ks < 11) {
                bf16_t* an = (bf16_t*)(smem + ARENA_OFF + (ks + 1) * ARENA_SZ);
                #pragma unroll
                for (int mi = 0; mi < 4; ++mi)
                    afn[mi] = *(const bf16x8*)(an + XF_ROW(mi) * AO_STRIDE + q4 * 8);
            }
            #pragma unroll
            for (int jj = 0; jj < 2; ++jj)
                #pragma unroll
                for (int mi = 0; mi < 4; ++mi)
                    pacc[jj][mi] = __builtin_amdgcn_mfma_f32_16x16x32_bf16(
                        afc[mi], w0[jj], pacc[jj][mi], 0, 0, 0);
            if (ks < 11) {
                #pragma unroll
                for (int jj = 0; jj < 2; ++jj) w0[jj] = w1[jj];
                if (ks < 10) {
                    #pragma unroll
                    for (int jj = 0; jj < 2; ++jj) w1[jj] = w2[jj];
                }
                #pragma unroll
                for (int mi = 0; mi < 4; ++mi) afc[mi] = afn[mi];
            }
        }
        float* og = out + (size_t)b * (N_ * C_);
        #pragma unroll
        for (int jj = 0; jj < 2; ++jj) {
            const int n = (wave * 2 + jj) * 16 + l15;
            const float bias = proj_b[n];
            #pragma unroll
            for (int mi = 0; mi < 4; ++mi) {
                #pragma unroll
                for (int r = 0; r < 4; ++r) {
                    const int m = mi * 16 + q4 * 4 + r;
                    if (m < N_) og[m * C_ + n] = pacc[jj][mi][r] + bias;
                }
            }
        }
    }
}

// ---------------------------------------------------------------------------
extern "C" void kernel_launch(void* const* d_in, const int* in_sizes, int n_in,
                              void* d_out, int out_size, void* d_ws, size_t ws_size,
                              hipStream_t stream)
{
    const float* x      = (const float*)d_in[0];
    const float* mask   = (const float*)d_in[1];
    const float* qkv_w  = (const float*)d_in[2];
    const float* qkv_b  = (const float*)d_in[3];
    const float* proj_w = (const float*)d_in[4];
    const float* proj_b = (const float*)d_in[5];
    const float* rpb    = (const float*)d_in[6];
    float* out = (float*)d_out;

    bf16_t* wqkvT  = (bf16_t*)d_ws;
    bf16_t* wprojT = wqkvT + WQKV_ELEMS;
    bf16_t* btbl   = wprojT + WPROJ_ELEMS;   // 64*12*49*64 bf16 = 4.8 MB

    prep_all<<<936 + NW_ * H_, 256, 0, stream>>>(qkv_w, proj_w, mask, rpb,
                                                 wqkvT, wprojT, btbl);
    fused_window_attn<<<2048, 768, 0, stream>>>(x, qkv_b, proj_b,
                                                wqkvT, wprojT, btbl, out);
}

// Round 14
// 506.928 us; speedup vs baseline: 1.1513x; 1.1513x over previous
//
#include <hip/hip_runtime.h>
#include <stdint.h>
#include <stddef.h>

typedef __bf16 bf16_t;
typedef __bf16 bf16x4 __attribute__((ext_vector_type(4)));
typedef __bf16 bf16x8 __attribute__((ext_vector_type(8)));
typedef float  f32x4  __attribute__((ext_vector_type(4)));

#define H_   12
#define N_   49
#define C_   384
#define D_   32
#define NW_  64
#define C3_  1152

// ---- LDS layout (bytes) ----
// xs: 49 x 392 bf16 (38416 B) -- shared x tile, read-only after B0.
// 12 per-wave arenas (9856 B each): private to wave h = head h.
//   bytes 0..3135   : q  [49][32] (stride 32) -- read by qf hoist only
//   bytes 3136..6271: k  [49][32] (stride 32) -- read by kf hoist only
//   bytes 6272..9855: vT [32][56]             -- cols 48..55 zeroed
// After the qf/kf hoists (P3 start), the arena is repurposed:
//   ao [49][40] (stride 40 -> bank-conflict-free b128 reads in P4):
//       bytes 0..3919  (q region + first 784 B of k)
//   P  16 x 72 elems: bytes 3920..6223  (k + 784, disjoint from ao)
// +16 B tail guard (last arena's vT b128 overrun).
#define XS_STRIDE 392
#define ARENA_OFF 38416
#define ARENA_SZ  9856
#define AK_OFF    3136
#define AV_OFF    6272
#define AV_STRIDE 56
#define AO_STRIDE 40            // elems; 80 B rows -> bank step 20 -> 2-way max
#define P_STRIDE  72
#define SMEM_BYTES 156704        // 38416 + 12*9856 + 16

#define WQKV_ELEMS  (C3_ * C_)   // 442368
#define WPROJ_ELEMS (C_ * C_)    // 147456

// padded row clamp: tile mi==3 covers toks 48..63; clamp to 48 (broadcast).
// Junk outputs are masked by the existing m<N_ / t0<N_ guards downstream.
#define XF_ROW(mi) ((mi) == 3 ? 48 : (mi) * 16 + l15)

// ---------------------------------------------------------------------------
// prep_all: merged weight transpose + bias table build (one launch).
// blocks 0..287: frag-order transpose of qkv_w/proj_w (16x16x32 order).
// blocks 288..1055: btbl[w][h][m][n] = (rpb+mask)*log2e, n padded to 64.
// ---------------------------------------------------------------------------
__global__ void prep_all(const float* __restrict__ qkv_w,
                         const float* __restrict__ proj_w,
                         const float* __restrict__ mask,
                         const float* __restrict__ rpb,
                         bf16_t* __restrict__ wqkvT,
                         bf16_t* __restrict__ wprojT,
                         bf16_t* __restrict__ btbl)
{
    __shared__ bf16_t tile[32][72];
    int bid = blockIdx.x;
    const int t = threadIdx.x;
    if (bid < 288) {
        const float* src; bf16_t* dst; int NC, ks, g;
        if (bid < 216) { src = qkv_w;  dst = wqkvT;  NC = C3_; ks = bid % 12; g = bid / 12; }
        else { bid -= 216; src = proj_w; dst = wprojT; NC = C_;  ks = bid % 12; g = bid / 12; }
        const int n0 = g * 64;
        const int r0 = t >> 6, cc = t & 63;
        #pragma unroll
        for (int p = 0; p < 8; ++p) {
            int row = p * 4 + r0;
            tile[row][cc] = (bf16_t)src[(ks * 32 + row) * NC + n0 + cc];
        }
        __syncthreads();
        const int lane = t & 63, ctl = t >> 6;
        const int q4 = lane >> 4, l15 = lane & 15;
        bf16x8 v;
        #pragma unroll
        for (int j = 0; j < 8; ++j) v[j] = tile[q4 * 8 + j][ctl * 16 + l15];
        *(bf16x8*)(dst + ((size_t)((g * 4 + ctl) * 12 + ks) * 64 + lane) * 8) = v;
    } else {
        bid -= 288;
        const int w = bid / H_, h = bid % H_;
        bf16_t* out = btbl + (size_t)(w * H_ + h) * (N_ * 64);
        for (int idx = t; idx < N_ * 64; idx += 256) {
            int m = idx >> 6, n = idx & 63;
            float v = 0.f;
            if (n < N_)
                v = (rpb[(h * N_ + m) * N_ + n] + mask[((size_t)w * N_ + m) * N_ + n])
                    * 1.4426950408889634f;
            out[idx] = (bf16_t)v;
        }
    }
}

// ---------------------------------------------------------------------------
// Head-decoupled fused kernel: one block per window, 12 waves = 12 heads.
// This round: P2's two 3-tile passes FUSED into one 6-tile pass over ks.
// xf[4] is loaded ONCE per K-step (was twice) -> P2 xf LDS reads halved,
// 48 b128/wave vs 96, attacking the most-loaded pipe (LDS ~36k cyc/blk).
// Same 16x16x32 MFMA shape (r11's 32x32 regressed: latency per K-step).
// Schedule keeps >=193cy load-use distance: wfB covered by group-1 MFMAs,
// wfA(ks+1) covered by group-2 MFMAs, xfn loaded a full iteration early.
// Barriers: B0 (xs staged) and B1 (all ao ready) only.
// ---------------------------------------------------------------------------
__global__ __launch_bounds__(768, 3)
void fused_window_attn(const float* __restrict__ x,
                       const float* __restrict__ qkv_b,
                       const float* __restrict__ proj_b,
                       const bf16_t* __restrict__ wqkvT,
                       const bf16_t* __restrict__ wprojT,
                       const bf16_t* __restrict__ btbl,
                       float* __restrict__ out)
{
    __shared__ __align__(16) unsigned char smem[SMEM_BYTES];
    bf16_t* xs = (bf16_t*)smem;

    const int tid  = threadIdx.x;
    const int wave = tid >> 6;                  // 0..11 = head
    const int lane = tid & 63;
    const int q4   = lane >> 4;
    const int l15  = lane & 15;
    const int b    = blockIdx.x;

    bf16_t* aq = (bf16_t*)(smem + ARENA_OFF + wave * ARENA_SZ);          // q, then ao
    bf16_t* ak = (bf16_t*)(smem + ARENA_OFF + wave * ARENA_SZ + AK_OFF); // k, then P
    bf16_t* av = (bf16_t*)(smem + ARENA_OFF + wave * ARENA_SZ + AV_OFF); // vT

    const f32x4 z4 = {0.f, 0.f, 0.f, 0.f};

    // ---------------- P1: zero own vT pad cols; stage x -> xs -------------
    {
        // vT cols 48..55 must be exact zeros (read x P==0 by PV b128;
        // 0*NaN = NaN). Epilogue B never writes cols >= 49.
        for (int t2 = lane; t2 < 256; t2 += 64) {
            int r = t2 >> 3, c = t2 & 7;
            av[r * AV_STRIDE + 48 + c] = (bf16_t)0.f;
        }
        if (tid < 8) ((bf16_t*)(smem + SMEM_BYTES - 16))[tid] = (bf16_t)0.f;

        const float* xg = x + (size_t)b * (N_ * C_);
        for (int t2 = tid; t2 < (N_ * C_) / 4; t2 += 768) {
            float4 v = ((const float4*)xg)[t2];
            int r = t2 / 96, c4 = t2 % 96;
            bf16x4 o;
            o[0] = (bf16_t)v.x; o[1] = (bf16_t)v.y;
            o[2] = (bf16_t)v.z; o[3] = (bf16_t)v.w;
            *(bf16x4*)(xs + r * XS_STRIDE + c4 * 4) = o;
        }
    }
    __syncthreads();   // B0: xs ready for all waves

    // ---------------- P2: qkv GEMM, single 6-tile pass --------------------
    // Wave h owns tiles {2h, 2h+1, 24+2h} (group 1, A-type) and
    // {24+2h+1 (A), 48+2h (B), 48+2h+1 (B)} (group 2).
    {
        const int tA0 = 2 * wave, tA1 = 2 * wave + 1, tA2 = 24 + 2 * wave;
        const int tA3 = 24 + 2 * wave + 1;
        const int tB0 = 48 + 2 * wave, tB1 = 48 + 2 * wave + 1;

        f32x4 acc[6][4];
        #pragma unroll
        for (int jj = 0; jj < 6; ++jj)
            #pragma unroll
            for (int mi = 0; mi < 4; ++mi) acc[jj][mi] = z4;

        bf16x8 wfA[3], wfB[3], xfc[4], xfn[4];
        wfA[0] = *(const bf16x8*)(wqkvT + ((size_t)(tA0 * 12) * 64 + lane) * 8);
        wfA[1] = *(const bf16x8*)(wqkvT + ((size_t)(tA1 * 12) * 64 + lane) * 8);
        wfA[2] = *(const bf16x8*)(wqkvT + ((size_t)(tA2 * 12) * 64 + lane) * 8);
        #pragma unroll
        for (int mi = 0; mi < 4; ++mi)
            xfc[mi] = *(const bf16x8*)(xs + XF_ROW(mi) * XS_STRIDE + q4 * 8);

        #pragma unroll
        for (int ks = 0; ks < 12; ++ks) {
            // group-2 weights for THIS ks (covered by group-1 MFMAs below)
            wfB[0] = *(const bf16x8*)(wqkvT + ((size_t)(tA3 * 12 + ks) * 64 + lane) * 8);
            wfB[1] = *(const bf16x8*)(wqkvT + ((size_t)(tB0 * 12 + ks) * 64 + lane) * 8);
            wfB[2] = *(const bf16x8*)(wqkvT + ((size_t)(tB1 * 12 + ks) * 64 + lane) * 8);
            if (ks < 11) {
                #pragma unroll
                for (int mi = 0; mi < 4; ++mi)
                    xfn[mi] = *(const bf16x8*)(xs + XF_ROW(mi) * XS_STRIDE
                                                  + (ks + 1) * 32 + q4 * 8);
            }
            // group 1: 12 MFMAs (A-type)
            #pragma unroll
            for (int jj = 0; jj < 3; ++jj)
                #pragma unroll
                for (int mi = 0; mi < 4; ++mi)
                    acc[jj][mi] = __builtin_amdgcn_mfma_f32_16x16x32_bf16(
                        wfA[jj], xfc[mi], acc[jj][mi], 0, 0, 0);
            // group-1 weights for ks+1 (covered by group-2 MFMAs below)
            if (ks < 11) {
                wfA[0] = *(const bf16x8*)(wqkvT + ((size_t)(tA0 * 12 + ks + 1) * 64 + lane) * 8);
                wfA[1] = *(const bf16x8*)(wqkvT + ((size_t)(tA1 * 12 + ks + 1) * 64 + lane) * 8);
                wfA[2] = *(const bf16x8*)(wqkvT + ((size_t)(tA2 * 12 + ks + 1) * 64 + lane) * 8);
            }
            // group 2: 12 MFMAs (A-type k1; B-type v0,v1)
            #pragma unroll
            for (int mi = 0; mi < 4; ++mi) {
                acc[3][mi] = __builtin_amdgcn_mfma_f32_16x16x32_bf16(
                    wfB[0], xfc[mi], acc[3][mi], 0, 0, 0);
                acc[4][mi] = __builtin_amdgcn_mfma_f32_16x16x32_bf16(
                    xfc[mi], wfB[1], acc[4][mi], 0, 0, 0);
                acc[5][mi] = __builtin_amdgcn_mfma_f32_16x16x32_bf16(
                    xfc[mi], wfB[2], acc[5][mi], 0, 0, 0);
            }
            if (ks < 11) {
                #pragma unroll
                for (int mi = 0; mi < 4; ++mi) xfc[mi] = xfn[mi];
            }
        }

        // ---- epilogue A: tiles 0..3 (chan=gt*16+q4*4+r, tok=mi*16+l15) ----
        // jj 0,1 (q tiles 2h,2h+1) -> aq local col jj*16+q4*4
        // jj 2,3 (k tiles 24+2h,24+2h+1) -> ak local col (jj-2)*16+q4*4
        // gt*16 is the RAW qkv_b column (q: 0..383, k: 384..767; no +C_).
        #pragma unroll
        for (int jj = 0; jj < 4; ++jj) {
            const int gt = (jj < 2) ? (2 * wave + jj) : (24 + 2 * wave + (jj - 2));
            const int gc = gt * 16 + q4 * 4;
            float4 bv = *(const float4*)(qkv_b + gc);
            bf16_t* dst = (jj < 2) ? aq : ak;
            const int cl = (jj & 1) * 16 + q4 * 4;
            #pragma unroll
            for (int mi = 0; mi < 4; ++mi) {
                const int m = mi * 16 + l15;
                if (m < N_) {
                    bf16x4 o;
                    o[0] = (bf16_t)(acc[jj][mi][0] + bv.x);
                    o[1] = (bf16_t)(acc[jj][mi][1] + bv.y);
                    o[2] = (bf16_t)(acc[jj][mi][2] + bv.z);
                    o[3] = (bf16_t)(acc[jj][mi][3] + bv.w);
                    *(bf16x4*)(dst + m * 32 + cl) = o;
                }
            }
        }
        // ---- epilogue B: tiles 4,5 -> vT (tok=mi*16+q4*4+r, dim=jv*16+l15)
        #pragma unroll
        for (int jv = 0; jv < 2; ++jv) {
            const int d  = jv * 16 + l15;                       // local dim
            const float bb = qkv_b[(48 + 2 * wave + jv) * 16 + l15];
            #pragma unroll
            for (int mi = 0; mi < 4; ++mi) {
                const int t0 = mi * 16 + q4 * 4;
                if (t0 + 3 < N_) {
                    bf16x4 o;
                    #pragma unroll
                    for (int r = 0; r < 4; ++r) o[r] = (bf16_t)(acc[4 + jv][mi][r] + bb);
                    *(bf16x4*)(av + d * AV_STRIDE + t0) = o;
                } else {
                    #pragma unroll
                    for (int r = 0; r < 4; ++r)
                        if (t0 + r < N_)
                            av[d * AV_STRIDE + t0 + r] = (bf16_t)(acc[4 + jv][mi][r] + bb);
                }
            }
        }
    }
    // NO barrier: wave h's arena is complete; proceed straight to attention.

    // ---------------- P3: attention for head h (private arena) ------------
    {
        bf16_t* pb = ak + 392;   // P at k+784 B (disjoint from ao's k spill)
        const bf16_t* tb = btbl + (size_t)((b & (NW_ - 1)) * H_ + wave) * (N_ * 64);
        const float SC = 0.17677669529663687f * 1.4426950408889634f;

        bf16x8 kf[4];
        #pragma unroll
        for (int ni = 0; ni < 4; ++ni) {
            const int kr = (ni == 3) ? 48 : ni * 16 + l15;
            kf[ni] = *(const bf16x8*)(ak + kr * 32 + q4 * 8);
        }
        bf16x8 vf[2][2];
        #pragma unroll
        for (int ks2 = 0; ks2 < 2; ++ks2)
            #pragma unroll
            for (int dt = 0; dt < 2; ++dt)
                vf[ks2][dt] = *(const bf16x8*)(av + (dt * 16 + l15) * AV_STRIDE
                                                  + ks2 * 32 + q4 * 8);
        bf16x8 qf[4];
        #pragma unroll
        for (int mt = 0; mt < 4; ++mt) {
            const int qr = (mt == 3) ? 48 : mt * 16 + l15;
            qf[mt] = *(const bf16x8*)(aq + qr * 32 + q4 * 8);
        }
        // q and k fully hoisted; arena repurposed: ao (stride 40) + P.

        #pragma unroll
        for (int mt = 0; mt < 4; ++mt) {
            f32x4 sacc[4];
            #pragma unroll
            for (int ni = 0; ni < 4; ++ni)
                sacc[ni] = __builtin_amdgcn_mfma_f32_16x16x32_bf16(
                    kf[ni], qf[mt], z4, 0, 0, 0);

            const int m  = mt * 16 + l15;
            const int mc = m < 48 ? m : 48;
            float den = 0.f;
            #pragma unroll
            for (int ni = 0; ni < 4; ++ni) {
                bf16x4 bv = *(const bf16x4*)(tb + (size_t)mc * 64 + ni * 16 + q4 * 4);
                #pragma unroll
                for (int r = 0; r < 4; ++r) {
                    const int n = ni * 16 + q4 * 4 + r;
                    float s = 0.f;
                    if (n < N_)
                        s = __builtin_exp2f(sacc[ni][r] * SC + (float)bv[r]);
                    sacc[ni][r] = s;
                    den += s;
                }
            }
            den += __shfl_xor(den, 16);
            den += __shfl_xor(den, 32);
            const float ri = __builtin_amdgcn_rcpf(den);

            // P write (exact zeros for n>=49; rows m>=49 skipped -> stale,
            // masked at ao staging)
            if (m < N_) {
                #pragma unroll
                for (int ni = 0; ni < 4; ++ni) {
                    bf16x4 o;
                    #pragma unroll
                    for (int r = 0; r < 4; ++r) o[r] = (bf16_t)(sacc[ni][r] * ri);
                    *(bf16x4*)(pb + l15 * P_STRIDE + ni * 16 + q4 * 4) = o;
                }
            }

            f32x4 o0 = z4, o1 = z4;
            #pragma unroll
            for (int ks2 = 0; ks2 < 2; ++ks2) {
                bf16x8 pf = *(const bf16x8*)(pb + l15 * P_STRIDE + ks2 * 32 + q4 * 8);
                o0 = __builtin_amdgcn_mfma_f32_16x16x32_bf16(pf, vf[ks2][0], o0, 0, 0, 0);
                o1 = __builtin_amdgcn_mfma_f32_16x16x32_bf16(pf, vf[ks2][1], o1, 0, 0, 0);
            }
            #pragma unroll
            for (int r = 0; r < 4; ++r) {
                const int ms = mt * 16 + q4 * 4 + r;
                if (ms < N_) {
                    aq[ms * AO_STRIDE + l15]      = (bf16_t)o0[r];
                    aq[ms * AO_STRIDE + 16 + l15] = (bf16_t)o1[r];
                }
            }
        }
    }
    __syncthreads();   // B1: all heads' ao staged in arenas

    // ---------------- P4: out = ao @ Wproj + b, 2 col-tiles/wave ----------
    {
        f32x4 pacc[2][4];
        #pragma unroll
        for (int jj = 0; jj < 2; ++jj)
            #pragma unroll
            for (int mi = 0; mi < 4; ++mi) pacc[jj][mi] = z4;

        bf16x8 w0[2], w1[2], w2[2], afc[4], afn[4];
        #pragma unroll
        for (int jj = 0; jj < 2; ++jj) {
            w0[jj] = *(const bf16x8*)(wprojT +
                ((size_t)((wave * 2 + jj) * 12 + 0) * 64 + lane) * 8);
            w1[jj] = *(const bf16x8*)(wprojT +
                ((size_t)((wave * 2 + jj) * 12 + 1) * 64 + lane) * 8);
        }
        #pragma unroll
        for (int mi = 0; mi < 4; ++mi)
            afc[mi] = *(const bf16x8*)((bf16_t*)(smem + ARENA_OFF)
                                       + XF_ROW(mi) * AO_STRIDE + q4 * 8);

        #pragma unroll
        for (int ks = 0; ks < 12; ++ks) {
            if (ks < 10) {
                #pragma unroll
                for (int jj = 0; jj < 2; ++jj)
                    w2[jj] = *(const bf16x8*)(wprojT +
                        ((size_t)((wave * 2 + jj) * 12 + ks + 2) * 64 + lane) * 8);
            }
            if (ks < 11) {
                bf16_t* an = (bf16_t*)(smem + ARENA_OFF + (ks + 1) * ARENA_SZ);
                #pragma unroll
                for (int mi = 0; mi < 4; ++mi)
                    afn[mi] = *(const bf16x8*)(an + XF_ROW(mi) * AO_STRIDE + q4 * 8);
            }
            #pragma unroll
            for (int jj = 0; jj < 2; ++jj)
                #pragma unroll
                for (int mi = 0; mi < 4; ++mi)
                    pacc[jj][mi] = __builtin_amdgcn_mfma_f32_16x16x32_bf16(
                        afc[mi], w0[jj], pacc[jj][mi], 0, 0, 0);
            if (ks < 11) {
                #pragma unroll
                for (int jj = 0; jj < 2; ++jj) w0[jj] = w1[jj];
                if (ks < 10) {
                    #pragma unroll
                    for (int jj = 0; jj < 2; ++jj) w1[jj] = w2[jj];
                }
                #pragma unroll
                for (int mi = 0; mi < 4; ++mi) afc[mi] = afn[mi];
            }
        }
        float* og = out + (size_t)b * (N_ * C_);
        #pragma unroll
        for (int jj = 0; jj < 2; ++jj) {
            const int n = (wave * 2 + jj) * 16 + l15;
            const float bias = proj_b[n];
            #pragma unroll
            for (int mi = 0; mi < 4; ++mi) {
                #pragma unroll
                for (int r = 0; r < 4; ++r) {
                    const int m = mi * 16 + q4 * 4 + r;
                    if (m < N_) og[m * C_ + n] = pacc[jj][mi][r] + bias;
                }
            }
        }
    }
}

// ---------------------------------------------------------------------------
extern "C" void kernel_launch(void* const* d_in, const int* in_sizes, int n_in,
                              void* d_out, int out_size, void* d_ws, size_t ws_size,
                              hipStream_t stream)
{
    const float* x      = (const float*)d_in[0];
    const float* mask   = (const float*)d_in[1];
    const float* qkv_w  = (const float*)d_in[2];
    const float* qkv_b  = (const float*)d_in[3];
    const float* proj_w = (const float*)d_in[4];
    const float* proj_b = (const float*)d_in[5];
    const float* rpb    = (const float*)d_in[6];
    float* out = (float*)d_out;

    bf16_t* wqkvT  = (bf16_t*)d_ws;
    bf16_t* wprojT = wqkvT + WQKV_ELEMS;
    bf16_t* btbl   = wprojT + WPROJ_ELEMS;   // 64*12*49*64 bf16 = 4.8 MB

    prep_all<<<288 + NW_ * H_, 256, 0, stream>>>(qkv_w, proj_w, mask, rpb,
                                                 wqkvT, wprojT, btbl);
    fused_window_attn<<<2048, 768, 0, stream>>>(x, qkv_b, proj_b,
                                                wqkvT, wprojT, btbl, out);
}

// Round 15
// 451.402 us; speedup vs baseline: 1.2929x; 1.1230x over previous
//
#include <hip/hip_runtime.h>
#include <stdint.h>
#include <stddef.h>

typedef __bf16 bf16_t;
typedef __bf16 bf16x4 __attribute__((ext_vector_type(4)));
typedef __bf16 bf16x8 __attribute__((ext_vector_type(8)));
typedef float  f32x4  __attribute__((ext_vector_type(4)));

#define H_   12
#define N_   49
#define C_   384
#define D_   32
#define NW_  64
#define C3_  1152

// ---- LDS layout (bytes) ----
// xs: 49 x 392 bf16 (38416 B) -- shared x tile, read-only after B0.
// 12 per-wave arenas (9856 B each): private to wave h = head h.
//   bytes 0..3135   : q  [49][32] (stride 32) -- read by qf hoist only
//   bytes 3136..6271: k  [49][32] (stride 32) -- read by kf hoist only
//   bytes 6272..9855: vT [32][56]             -- cols 48..55 zeroed
// After the qf/kf hoists (P3 start), the arena is repurposed:
//   ao [49][40] (stride 40 -> bank-conflict-free b128 reads in P4):
//       bytes 0..3919  (q region + first 784 B of k)
//   P  16 x 72 elems: bytes 3920..6223  (k + 784, disjoint from ao)
// +16 B tail guard (last arena's vT b128 overrun).
#define XS_STRIDE 392
#define ARENA_OFF 38416
#define ARENA_SZ  9856
#define AK_OFF    3136
#define AV_OFF    6272
#define AV_STRIDE 56
#define AO_STRIDE 40            // elems; 80 B rows -> bank step 20 -> 2-way max
#define P_STRIDE  72
#define SMEM_BYTES 156704        // 38416 + 12*9856 + 16

#define WQKV_ELEMS  (C3_ * C_)   // 442368
#define WPROJ_ELEMS (C_ * C_)    // 147456

// padded row clamp: tile mi==3 covers toks 48..63; clamp to 48 (broadcast).
// Junk outputs are masked by the existing m<N_ / t0<N_ guards downstream.
#define XF_ROW(mi) ((mi) == 3 ? 48 : (mi) * 16 + l15)

// ---------------------------------------------------------------------------
// prep_all: merged weight transpose + bias table build (one launch).
// blocks 0..287: frag-order transpose of qkv_w/proj_w (16x16x32 order).
// blocks 288..1055: btbl[w][h][m][n] = (rpb+mask)*log2e, n padded to 64.
// ---------------------------------------------------------------------------
__global__ void prep_all(const float* __restrict__ qkv_w,
                         const float* __restrict__ proj_w,
                         const float* __restrict__ mask,
                         const float* __restrict__ rpb,
                         bf16_t* __restrict__ wqkvT,
                         bf16_t* __restrict__ wprojT,
                         bf16_t* __restrict__ btbl)
{
    __shared__ bf16_t tile[32][72];
    int bid = blockIdx.x;
    const int t = threadIdx.x;
    if (bid < 288) {
        const float* src; bf16_t* dst; int NC, ks, g;
        if (bid < 216) { src = qkv_w;  dst = wqkvT;  NC = C3_; ks = bid % 12; g = bid / 12; }
        else { bid -= 216; src = proj_w; dst = wprojT; NC = C_;  ks = bid % 12; g = bid / 12; }
        const int n0 = g * 64;
        const int r0 = t >> 6, cc = t & 63;
        #pragma unroll
        for (int p = 0; p < 8; ++p) {
            int row = p * 4 + r0;
            tile[row][cc] = (bf16_t)src[(ks * 32 + row) * NC + n0 + cc];
        }
        __syncthreads();
        const int lane = t & 63, ctl = t >> 6;
        const int q4 = lane >> 4, l15 = lane & 15;
        bf16x8 v;
        #pragma unroll
        for (int j = 0; j < 8; ++j) v[j] = tile[q4 * 8 + j][ctl * 16 + l15];
        *(bf16x8*)(dst + ((size_t)((g * 4 + ctl) * 12 + ks) * 64 + lane) * 8) = v;
    } else {
        bid -= 288;
        const int w = bid / H_, h = bid % H_;
        bf16_t* out = btbl + (size_t)(w * H_ + h) * (N_ * 64);
        for (int idx = t; idx < N_ * 64; idx += 256) {
            int m = idx >> 6, n = idx & 63;
            float v = 0.f;
            if (n < N_)
                v = (rpb[(h * N_ + m) * N_ + n] + mask[((size_t)w * N_ + m) * N_ + n])
                    * 1.4426950408889634f;
            out[idx] = (bf16_t)v;
        }
    }
}

// ---------------------------------------------------------------------------
// Head-decoupled fused kernel: one block per window, 12 waves = 12 heads.
// Wave h owns head h end-to-end (private arena, no P2->P3 barrier; waves
// skew freely between B0 and B1). This round: s_setprio(1) around every
// MFMA cluster (P2 groups, P3 QK/PV, P4) -- with skewed waves the CU
// scheduler can now prefer the MFMA-issuing wave at arbitration (T5
// mechanism; was correctly null pre-skew in r7's lockstep structure).
// Barriers: B0 (xs staged) and B1 (all ao ready) only.
// ---------------------------------------------------------------------------
__global__ __launch_bounds__(768, 3)
void fused_window_attn(const float* __restrict__ x,
                       const float* __restrict__ qkv_b,
                       const float* __restrict__ proj_b,
                       const bf16_t* __restrict__ wqkvT,
                       const bf16_t* __restrict__ wprojT,
                       const bf16_t* __restrict__ btbl,
                       float* __restrict__ out)
{
    __shared__ __align__(16) unsigned char smem[SMEM_BYTES];
    bf16_t* xs = (bf16_t*)smem;

    const int tid  = threadIdx.x;
    const int wave = tid >> 6;                  // 0..11 = head
    const int lane = tid & 63;
    const int q4   = lane >> 4;
    const int l15  = lane & 15;
    const int b    = blockIdx.x;

    bf16_t* aq = (bf16_t*)(smem + ARENA_OFF + wave * ARENA_SZ);          // q, then ao
    bf16_t* ak = (bf16_t*)(smem + ARENA_OFF + wave * ARENA_SZ + AK_OFF); // k, then P
    bf16_t* av = (bf16_t*)(smem + ARENA_OFF + wave * ARENA_SZ + AV_OFF); // vT

    const f32x4 z4 = {0.f, 0.f, 0.f, 0.f};

    // ---------------- P1: zero own vT pad cols; stage x -> xs -------------
    {
        // vT cols 48..55 must be exact zeros (read x P==0 by PV b128;
        // 0*NaN = NaN). Epilogue B never writes cols >= 49.
        for (int t2 = lane; t2 < 256; t2 += 64) {
            int r = t2 >> 3, c = t2 & 7;
            av[r * AV_STRIDE + 48 + c] = (bf16_t)0.f;
        }
        if (tid < 8) ((bf16_t*)(smem + SMEM_BYTES - 16))[tid] = (bf16_t)0.f;

        const float* xg = x + (size_t)b * (N_ * C_);
        for (int t2 = tid; t2 < (N_ * C_) / 4; t2 += 768) {
            float4 v = ((const float4*)xg)[t2];
            int r = t2 / 96, c4 = t2 % 96;
            bf16x4 o;
            o[0] = (bf16_t)v.x; o[1] = (bf16_t)v.y;
            o[2] = (bf16_t)v.z; o[3] = (bf16_t)v.w;
            *(bf16x4*)(xs + r * XS_STRIDE + c4 * 4) = o;
        }
    }
    __syncthreads();   // B0: xs ready for all waves

    // ---------------- P2 pass 0: tiles {2h, 2h+1, 24+2h}, all A-type ------
    {
        const int tA0 = 2 * wave, tA1 = 2 * wave + 1, tA2 = 24 + 2 * wave;
        f32x4 acc[3][4];
        #pragma unroll
        for (int jj = 0; jj < 3; ++jj)
            #pragma unroll
            for (int mi = 0; mi < 4; ++mi) acc[jj][mi] = z4;

        bf16x8 wfc[3], xfc[4];
        wfc[0] = *(const bf16x8*)(wqkvT + ((size_t)(tA0 * 12) * 64 + lane) * 8);
        wfc[1] = *(const bf16x8*)(wqkvT + ((size_t)(tA1 * 12) * 64 + lane) * 8);
        wfc[2] = *(const bf16x8*)(wqkvT + ((size_t)(tA2 * 12) * 64 + lane) * 8);
        #pragma unroll
        for (int mi = 0; mi < 4; ++mi)
            xfc[mi] = *(const bf16x8*)(xs + XF_ROW(mi) * XS_STRIDE + q4 * 8);

        #pragma unroll
        for (int ks = 0; ks < 12; ++ks) {
            bf16x8 wfn[3], xfn[4];
            if (ks < 11) {
                wfn[0] = *(const bf16x8*)(wqkvT + ((size_t)(tA0 * 12 + ks + 1) * 64 + lane) * 8);
                wfn[1] = *(const bf16x8*)(wqkvT + ((size_t)(tA1 * 12 + ks + 1) * 64 + lane) * 8);
                wfn[2] = *(const bf16x8*)(wqkvT + ((size_t)(tA2 * 12 + ks + 1) * 64 + lane) * 8);
                #pragma unroll
                for (int mi = 0; mi < 4; ++mi)
                    xfn[mi] = *(const bf16x8*)(xs + XF_ROW(mi) * XS_STRIDE
                                                  + (ks + 1) * 32 + q4 * 8);
            }
            __builtin_amdgcn_s_setprio(1);
            #pragma unroll
            for (int jj = 0; jj < 3; ++jj)
                #pragma unroll
                for (int mi = 0; mi < 4; ++mi)
                    acc[jj][mi] = __builtin_amdgcn_mfma_f32_16x16x32_bf16(
                        wfc[jj], xfc[mi], acc[jj][mi], 0, 0, 0);
            __builtin_amdgcn_s_setprio(0);
            if (ks < 11) {
                #pragma unroll
                for (int jj = 0; jj < 3; ++jj) wfc[jj] = wfn[jj];
                #pragma unroll
                for (int mi = 0; mi < 4; ++mi) xfc[mi] = xfn[mi];
            }
        }
        // epilogue A: (chan=ct*16+q4*4+r, tok=l15) -> q/k [tok][chan]
        #pragma unroll
        for (int jj = 0; jj < 3; ++jj) {
            const int gt = (jj < 2) ? (2 * wave + jj) : (24 + 2 * wave);
            const int gc = gt * 16 + q4 * 4;
            bf16_t* dst = (jj < 2) ? aq : ak;
            const int cl = (jj < 2) ? (jj * 16 + q4 * 4) : (q4 * 4);
            float4 bv = *(const float4*)(qkv_b + gc);
            #pragma unroll
            for (int mi = 0; mi < 4; ++mi) {
                const int m = mi * 16 + l15;
                if (m < N_) {
                    bf16x4 o;
                    o[0] = (bf16_t)(acc[jj][mi][0] + bv.x);
                    o[1] = (bf16_t)(acc[jj][mi][1] + bv.y);
                    o[2] = (bf16_t)(acc[jj][mi][2] + bv.z);
                    o[3] = (bf16_t)(acc[jj][mi][3] + bv.w);
                    *(bf16x4*)(dst + m * 32 + cl) = o;
                }
            }
        }
    }

    // ---------------- P2 pass 1: {24+2h+1 (A), 48+2h (B), 48+2h+1 (B)} ----
    {
        const int tA = 24 + 2 * wave + 1;
        const int tB0 = 48 + 2 * wave, tB1 = 48 + 2 * wave + 1;
        f32x4 acc[3][4];
        #pragma unroll
        for (int jj = 0; jj < 3; ++jj)
            #pragma unroll
            for (int mi = 0; mi < 4; ++mi) acc[jj][mi] = z4;

        bf16x8 wfc[3], xfc[4];
        wfc[0] = *(const bf16x8*)(wqkvT + ((size_t)(tA * 12) * 64 + lane) * 8);
        wfc[1] = *(const bf16x8*)(wqkvT + ((size_t)(tB0 * 12) * 64 + lane) * 8);
        wfc[2] = *(const bf16x8*)(wqkvT + ((size_t)(tB1 * 12) * 64 + lane) * 8);
        #pragma unroll
        for (int mi = 0; mi < 4; ++mi)
            xfc[mi] = *(const bf16x8*)(xs + XF_ROW(mi) * XS_STRIDE + q4 * 8);

        #pragma unroll
        for (int ks = 0; ks < 12; ++ks) {
            bf16x8 wfn[3], xfn[4];
            if (ks < 11) {
                wfn[0] = *(const bf16x8*)(wqkvT + ((size_t)(tA * 12 + ks + 1) * 64 + lane) * 8);
                wfn[1] = *(const bf16x8*)(wqkvT + ((size_t)(tB0 * 12 + ks + 1) * 64 + lane) * 8);
                wfn[2] = *(const bf16x8*)(wqkvT + ((size_t)(tB1 * 12 + ks + 1) * 64 + lane) * 8);
                #pragma unroll
                for (int mi = 0; mi < 4; ++mi)
                    xfn[mi] = *(const bf16x8*)(xs + XF_ROW(mi) * XS_STRIDE
                                                  + (ks + 1) * 32 + q4 * 8);
            }
            __builtin_amdgcn_s_setprio(1);
            #pragma unroll
            for (int mi = 0; mi < 4; ++mi) {
                acc[0][mi] = __builtin_amdgcn_mfma_f32_16x16x32_bf16(
                    wfc[0], xfc[mi], acc[0][mi], 0, 0, 0);      // A-type (k1)
                acc[1][mi] = __builtin_amdgcn_mfma_f32_16x16x32_bf16(
                    xfc[mi], wfc[1], acc[1][mi], 0, 0, 0);      // B-type (v0)
                acc[2][mi] = __builtin_amdgcn_mfma_f32_16x16x32_bf16(
                    xfc[mi], wfc[2], acc[2][mi], 0, 0, 0);      // B-type (v1)
            }
            __builtin_amdgcn_s_setprio(0);
            if (ks < 11) {
                #pragma unroll
                for (int jj = 0; jj < 3; ++jj) wfc[jj] = wfn[jj];
                #pragma unroll
                for (int mi = 0; mi < 4; ++mi) xfc[mi] = xfn[mi];
            }
        }
        // epilogue A for k1 -> k arena local col 16+q4*4
        {
            const int gc = tA * 16 + q4 * 4;
            float4 bv = *(const float4*)(qkv_b + gc);
            #pragma unroll
            for (int mi = 0; mi < 4; ++mi) {
                const int m = mi * 16 + l15;
                if (m < N_) {
                    bf16x4 o;
                    o[0] = (bf16_t)(acc[0][mi][0] + bv.x);
                    o[1] = (bf16_t)(acc[0][mi][1] + bv.y);
                    o[2] = (bf16_t)(acc[0][mi][2] + bv.z);
                    o[3] = (bf16_t)(acc[0][mi][3] + bv.w);
                    *(bf16x4*)(ak + m * 32 + 16 + q4 * 4) = o;
                }
            }
        }
        // epilogue B for v0,v1 -> vT arena [dim local][tok]
        #pragma unroll
        for (int jv = 0; jv < 2; ++jv) {
            const int d  = jv * 16 + l15;                       // local dim
            const float bb = qkv_b[(48 + 2 * wave + jv) * 16 + l15];
            #pragma unroll
            for (int mi = 0; mi < 4; ++mi) {
                const int t0 = mi * 16 + q4 * 4;
                if (t0 + 3 < N_) {
                    bf16x4 o;
                    #pragma unroll
                    for (int r = 0; r < 4; ++r) o[r] = (bf16_t)(acc[1 + jv][mi][r] + bb);
                    *(bf16x4*)(av + d * AV_STRIDE + t0) = o;
                } else {
                    #pragma unroll
                    for (int r = 0; r < 4; ++r)
                        if (t0 + r < N_)
                            av[d * AV_STRIDE + t0 + r] = (bf16_t)(acc[1 + jv][mi][r] + bb);
                }
            }
        }
    }
    // NO barrier: wave h's arena is complete; proceed straight to attention.

    // ---------------- P3: attention for head h (private arena) ------------
    {
        bf16_t* pb = ak + 392;   // P at k+784 B (disjoint from ao's k spill)
        const bf16_t* tb = btbl + (size_t)((b & (NW_ - 1)) * H_ + wave) * (N_ * 64);
        const float SC = 0.17677669529663687f * 1.4426950408889634f;

        bf16x8 kf[4];
        #pragma unroll
        for (int ni = 0; ni < 4; ++ni) {
            const int kr = (ni == 3) ? 48 : ni * 16 + l15;
            kf[ni] = *(const bf16x8*)(ak + kr * 32 + q4 * 8);
        }
        bf16x8 vf[2][2];
        #pragma unroll
        for (int ks2 = 0; ks2 < 2; ++ks2)
            #pragma unroll
            for (int dt = 0; dt < 2; ++dt)
                vf[ks2][dt] = *(const bf16x8*)(av + (dt * 16 + l15) * AV_STRIDE
                                                  + ks2 * 32 + q4 * 8);
        bf16x8 qf[4];
        #pragma unroll
        for (int mt = 0; mt < 4; ++mt) {
            const int qr = (mt == 3) ? 48 : mt * 16 + l15;
            qf[mt] = *(const bf16x8*)(aq + qr * 32 + q4 * 8);
        }
        // q and k fully hoisted; arena repurposed: ao (stride 40) + P.

        #pragma unroll
        for (int mt = 0; mt < 4; ++mt) {
            f32x4 sacc[4];
            __builtin_amdgcn_s_setprio(1);
            #pragma unroll
            for (int ni = 0; ni < 4; ++ni)
                sacc[ni] = __builtin_amdgcn_mfma_f32_16x16x32_bf16(
                    kf[ni], qf[mt], z4, 0, 0, 0);
            __builtin_amdgcn_s_setprio(0);

            const int m  = mt * 16 + l15;
            const int mc = m < 48 ? m : 48;
            float den = 0.f;
            #pragma unroll
            for (int ni = 0; ni < 4; ++ni) {
                bf16x4 bv = *(const bf16x4*)(tb + (size_t)mc * 64 + ni * 16 + q4 * 4);
                #pragma unroll
                for (int r = 0; r < 4; ++r) {
                    const int n = ni * 16 + q4 * 4 + r;
                    float s = 0.f;
                    if (n < N_)
                        s = __builtin_exp2f(sacc[ni][r] * SC + (float)bv[r]);
                    sacc[ni][r] = s;
                    den += s;
                }
            }
            den += __shfl_xor(den, 16);
            den += __shfl_xor(den, 32);
            const float ri = __builtin_amdgcn_rcpf(den);

            // P write (exact zeros for n>=49; rows m>=49 skipped -> stale,
            // masked at ao staging)
            if (m < N_) {
                #pragma unroll
                for (int ni = 0; ni < 4; ++ni) {
                    bf16x4 o;
                    #pragma unroll
                    for (int r = 0; r < 4; ++r) o[r] = (bf16_t)(sacc[ni][r] * ri);
                    *(bf16x4*)(pb + l15 * P_STRIDE + ni * 16 + q4 * 4) = o;
                }
            }

            f32x4 o0 = z4, o1 = z4;
            __builtin_amdgcn_s_setprio(1);
            #pragma unroll
            for (int ks2 = 0; ks2 < 2; ++ks2) {
                bf16x8 pf = *(const bf16x8*)(pb + l15 * P_STRIDE + ks2 * 32 + q4 * 8);
                o0 = __builtin_amdgcn_mfma_f32_16x16x32_bf16(pf, vf[ks2][0], o0, 0, 0, 0);
                o1 = __builtin_amdgcn_mfma_f32_16x16x32_bf16(pf, vf[ks2][1], o1, 0, 0, 0);
            }
            __builtin_amdgcn_s_setprio(0);
            #pragma unroll
            for (int r = 0; r < 4; ++r) {
                const int ms = mt * 16 + q4 * 4 + r;
                if (ms < N_) {
                    aq[ms * AO_STRIDE + l15]      = (bf16_t)o0[r];
                    aq[ms * AO_STRIDE + 16 + l15] = (bf16_t)o1[r];
                }
            }
        }
    }
    __syncthreads();   // B1: all heads' ao staged in arenas

    // ---------------- P4: out = ao @ Wproj + b, 2 col-tiles/wave ----------
    {
        f32x4 pacc[2][4];
        #pragma unroll
        for (int jj = 0; jj < 2; ++jj)
            #pragma unroll
            for (int mi = 0; mi < 4; ++mi) pacc[jj][mi] = z4;

        bf16x8 w0[2], w1[2], afc[4], afn[4];
        #pragma unroll
        for (int jj = 0; jj < 2; ++jj) {
            w0[jj] = *(const bf16x8*)(wprojT +
                ((size_t)((wave * 2 + jj) * 12 + 0) * 64 + lane) * 8);
            w1[jj] = *(const bf16x8*)(wprojT +
                ((size_t)((wave * 2 + jj) * 12 + 1) * 64 + lane) * 8);
        }
        #pragma unroll
        for (int mi = 0; mi < 4; ++mi)
            afc[mi] = *(const bf16x8*)((bf16_t*)(smem + ARENA_OFF)
                                       + XF_ROW(mi) * AO_STRIDE + q4 * 8);

        #pragma unroll
        for (int ks = 0; ks < 12; ++ks) {
            bf16x8 w2[2];
            if (ks < 10) {
                #pragma unroll
                for (int jj = 0; jj < 2; ++jj)
                    w2[jj] = *(const bf16x8*)(wprojT +
                        ((size_t)((wave * 2 + jj) * 12 + ks + 2) * 64 + lane) * 8);
            }
            if (ks < 11) {
                bf16_t* an = (bf16_t*)(smem + ARENA_OFF + (ks + 1) * ARENA_SZ);
                #pragma unroll
                for (int mi = 0; mi < 4; ++mi)
                    afn[mi] = *(const bf16x8*)(an + XF_ROW(mi) * AO_STRIDE + q4 * 8);
            }
            __builtin_amdgcn_s_setprio(1);
            #pragma unroll
            for (int jj = 0; jj < 2; ++jj)
                #pragma unroll
                for (int mi = 0; mi < 4; ++mi)
                    pacc[jj][mi] = __builtin_amdgcn_mfma_f32_16x16x32_bf16(
                        afc[mi], w0[jj], pacc[jj][mi], 0, 0, 0);
            __builtin_amdgcn_s_setprio(0);
            if (ks < 11) {
                #pragma unroll
                for (int jj = 0; jj < 2; ++jj) w0[jj] = w1[jj];
                if (ks < 10) {
                    #pragma unroll
                    for (int jj = 0; jj < 2; ++jj) w1[jj] = w2[jj];
                }
                #pragma unroll
                for (int mi = 0; mi < 4; ++mi) afc[mi] = afn[mi];
            }
        }
        float* og = out + (size_t)b * (N_ * C_);
        #pragma unroll
        for (int jj = 0; jj < 2; ++jj) {
            const int n = (wave * 2 + jj) * 16 + l15;
            const float bias = proj_b[n];
            #pragma unroll
            for (int mi = 0; mi < 4; ++mi) {
                #pragma unroll
                for (int r = 0; r < 4; ++r) {
                    const int m = mi * 16 + q4 * 4 + r;
                    if (m < N_) og[m * C_ + n] = pacc[jj][mi][r] + bias;
                }
            }
        }
    }
}

// ---------------------------------------------------------------------------
extern "C" void kernel_launch(void* const* d_in, const int* in_sizes, int n_in,
                              void* d_out, int out_size, void* d_ws, size_t ws_size,
                              hipStream_t stream)
{
    const float* x      = (const float*)d_in[0];
    const float* mask   = (const float*)d_in[1];
    const float* qkv_w  = (const float*)d_in[2];
    const float* qkv_b  = (const float*)d_in[3];
    const float* proj_w = (const float*)d_in[4];
    const float* proj_b = (const float*)d_in[5];
    const float* rpb    = (const float*)d_in[6];
    float* out = (float*)d_out;

    bf16_t* wqkvT  = (bf16_t*)d_ws;
    bf16_t* wprojT = wqkvT + WQKV_ELEMS;
    bf16_t* btbl   = wprojT + WPROJ_ELEMS;   // 64*12*49*64 bf16 = 4.8 MB

    prep_all<<<288 + NW_ * H_, 256, 0, stream>>>(qkv_w, proj_w, mask, rpb,
                                                 wqkvT, wprojT, btbl);
    fused_window_attn<<<2048, 768, 0, stream>>>(x, qkv_b, proj_b,
                                                wqkvT, wprojT, btbl, out);
}

// Round 16
// 442.324 us; speedup vs baseline: 1.3194x; 1.0205x over previous
//
#include <hip/hip_runtime.h>
#include <stdint.h>
#include <stddef.h>

typedef __bf16 bf16_t;
typedef __bf16 bf16x4 __attribute__((ext_vector_type(4)));
typedef __bf16 bf16x8 __attribute__((ext_vector_type(8)));
typedef float  f32x4  __attribute__((ext_vector_type(4)));

#define H_   12
#define N_   49
#define C_   384
#define D_   32
#define NW_  64
#define C3_  1152

// ---- LDS layout (bytes) ----
// xs: 49 x 392 bf16 (38416 B) -- shared x tile, read-only after B0.
// 12 per-wave arenas (9856 B each): private to wave h = head h.
//   bytes 0..3135   : q  [49][32] (stride 32, XOR-swizzled rows)
//   bytes 3136..6271: k  [49][32] (stride 32, XOR-swizzled rows)
//   bytes 6272..9855: vT [32][56]             -- cols 48..55 zeroed
// q/k rows are 64 B -> 16 l15-lanes alias 2 banks (8-way conflict).
// Swizzle: byte ^= ((row&3)<<4) -- bijective WITHIN the 64B row (bits 4-5
// only; (row&7)<<4 would flip bit 6 and cross rows), keeps 8B/16B align,
// spreads lanes over 4 bank-groups -> 4-way. Row 48 (clamped dup) has
// row&3==0 on both write and read -> consistent.
// After the qf/kf hoists (P3 start), the arena is repurposed:
//   ao [49][40] (stride 40, unswizzled) bytes 0..3919
//   P  16 x 72 elems: bytes 3920..6223  (k + 784, disjoint from ao)
// +16 B tail guard (last arena's vT b128 overrun).
#define XS_STRIDE 392
#define ARENA_OFF 38416
#define ARENA_SZ  9856
#define AK_OFF    3136
#define AV_OFF    6272
#define AV_STRIDE 56
#define AO_STRIDE 40            // elems; 80 B rows -> bank step 20 -> 2-way max
#define P_STRIDE  72
#define SMEM_BYTES 156704        // 38416 + 12*9856 + 16

#define QKSWZ(row, colbyte) (((row) * 64 + (colbyte)) ^ ((((row) & 3)) << 4))

#define WQKV_ELEMS  (C3_ * C_)   // 442368
#define WPROJ_ELEMS (C_ * C_)    // 147456

// padded row clamp: tile mi==3 covers toks 48..63; clamp to 48 (broadcast).
// Junk outputs are masked by the existing m<N_ / t0<N_ guards downstream.
#define XF_ROW(mi) ((mi) == 3 ? 48 : (mi) * 16 + l15)

// ---------------------------------------------------------------------------
// prep_all: merged weight transpose + bias table build (one launch).
// blocks 0..287: frag-order transpose of qkv_w/proj_w (16x16x32 order).
// blocks 288..1055: btbl[w][h][m][n] = (rpb+mask)*log2e, n padded to 64.
// ---------------------------------------------------------------------------
__global__ void prep_all(const float* __restrict__ qkv_w,
                         const float* __restrict__ proj_w,
                         const float* __restrict__ mask,
                         const float* __restrict__ rpb,
                         bf16_t* __restrict__ wqkvT,
                         bf16_t* __restrict__ wprojT,
                         bf16_t* __restrict__ btbl)
{
    __shared__ bf16_t tile[32][72];
    int bid = blockIdx.x;
    const int t = threadIdx.x;
    if (bid < 288) {
        const float* src; bf16_t* dst; int NC, ks, g;
        if (bid < 216) { src = qkv_w;  dst = wqkvT;  NC = C3_; ks = bid % 12; g = bid / 12; }
        else { bid -= 216; src = proj_w; dst = wprojT; NC = C_;  ks = bid % 12; g = bid / 12; }
        const int n0 = g * 64;
        const int r0 = t >> 6, cc = t & 63;
        #pragma unroll
        for (int p = 0; p < 8; ++p) {
            int row = p * 4 + r0;
            tile[row][cc] = (bf16_t)src[(ks * 32 + row) * NC + n0 + cc];
        }
        __syncthreads();
        const int lane = t & 63, ctl = t >> 6;
        const int q4 = lane >> 4, l15 = lane & 15;
        bf16x8 v;
        #pragma unroll
        for (int j = 0; j < 8; ++j) v[j] = tile[q4 * 8 + j][ctl * 16 + l15];
        *(bf16x8*)(dst + ((size_t)((g * 4 + ctl) * 12 + ks) * 64 + lane) * 8) = v;
    } else {
        bid -= 288;
        const int w = bid / H_, h = bid % H_;
        bf16_t* out = btbl + (size_t)(w * H_ + h) * (N_ * 64);
        for (int idx = t; idx < N_ * 64; idx += 256) {
            int m = idx >> 6, n = idx & 63;
            float v = 0.f;
            if (n < N_)
                v = (rpb[(h * N_ + m) * N_ + n] + mask[((size_t)w * N_ + m) * N_ + n])
                    * 1.4426950408889634f;
            out[idx] = (bf16_t)v;
        }
    }
}

// ---------------------------------------------------------------------------
// Head-decoupled fused kernel: one block per window, 12 waves = 12 heads.
// Wave h owns head h end-to-end (private arena, no P2->P3 barrier; waves
// skew freely between B0 and B1). setprio(1) around every MFMA cluster
// (r15: +7%). This round: q/k arena XOR-swizzle (8-way -> 4-way bank
// conflicts on epilogue-A writes and qf/kf hoist reads).
// Barriers: B0 (xs staged) and B1 (all ao ready) only.
// ---------------------------------------------------------------------------
__global__ __launch_bounds__(768, 3)
void fused_window_attn(const float* __restrict__ x,
                       const float* __restrict__ qkv_b,
                       const float* __restrict__ proj_b,
                       const bf16_t* __restrict__ wqkvT,
                       const bf16_t* __restrict__ wprojT,
                       const bf16_t* __restrict__ btbl,
                       float* __restrict__ out)
{
    __shared__ __align__(16) unsigned char smem[SMEM_BYTES];
    bf16_t* xs = (bf16_t*)smem;

    const int tid  = threadIdx.x;
    const int wave = tid >> 6;                  // 0..11 = head
    const int lane = tid & 63;
    const int q4   = lane >> 4;
    const int l15  = lane & 15;
    const int b    = blockIdx.x;

    unsigned char* aqB = smem + ARENA_OFF + wave * ARENA_SZ;             // q bytes
    unsigned char* akB = aqB + AK_OFF;                                   // k bytes
    bf16_t* aq = (bf16_t*)aqB;                  // q (swz), then ao (linear)
    bf16_t* ak = (bf16_t*)akB;                  // k (swz), then P (linear)
    bf16_t* av = (bf16_t*)(aqB + AV_OFF);       // vT

    const f32x4 z4 = {0.f, 0.f, 0.f, 0.f};

    // ---------------- P1: zero own vT pad cols; stage x -> xs -------------
    {
        // vT cols 48..55 must be exact zeros (read x P==0 by PV b128;
        // 0*NaN = NaN). Epilogue B never writes cols >= 49.
        for (int t2 = lane; t2 < 256; t2 += 64) {
            int r = t2 >> 3, c = t2 & 7;
            av[r * AV_STRIDE + 48 + c] = (bf16_t)0.f;
        }
        if (tid < 8) ((bf16_t*)(smem + SMEM_BYTES - 16))[tid] = (bf16_t)0.f;

        const float* xg = x + (size_t)b * (N_ * C_);
        for (int t2 = tid; t2 < (N_ * C_) / 4; t2 += 768) {
            float4 v = ((const float4*)xg)[t2];
            int r = t2 / 96, c4 = t2 % 96;
            bf16x4 o;
            o[0] = (bf16_t)v.x; o[1] = (bf16_t)v.y;
            o[2] = (bf16_t)v.z; o[3] = (bf16_t)v.w;
            *(bf16x4*)(xs + r * XS_STRIDE + c4 * 4) = o;
        }
    }
    __syncthreads();   // B0: xs ready for all waves

    // ---------------- P2 pass 0: tiles {2h, 2h+1, 24+2h}, all A-type ------
    {
        const int tA0 = 2 * wave, tA1 = 2 * wave + 1, tA2 = 24 + 2 * wave;
        f32x4 acc[3][4];
        #pragma unroll
        for (int jj = 0; jj < 3; ++jj)
            #pragma unroll
            for (int mi = 0; mi < 4; ++mi) acc[jj][mi] = z4;

        bf16x8 wfc[3], xfc[4];
        wfc[0] = *(const bf16x8*)(wqkvT + ((size_t)(tA0 * 12) * 64 + lane) * 8);
        wfc[1] = *(const bf16x8*)(wqkvT + ((size_t)(tA1 * 12) * 64 + lane) * 8);
        wfc[2] = *(const bf16x8*)(wqkvT + ((size_t)(tA2 * 12) * 64 + lane) * 8);
        #pragma unroll
        for (int mi = 0; mi < 4; ++mi)
            xfc[mi] = *(const bf16x8*)(xs + XF_ROW(mi) * XS_STRIDE + q4 * 8);

        #pragma unroll
        for (int ks = 0; ks < 12; ++ks) {
            bf16x8 wfn[3], xfn[4];
            if (ks < 11) {
                wfn[0] = *(const bf16x8*)(wqkvT + ((size_t)(tA0 * 12 + ks + 1) * 64 + lane) * 8);
                wfn[1] = *(const bf16x8*)(wqkvT + ((size_t)(tA1 * 12 + ks + 1) * 64 + lane) * 8);
                wfn[2] = *(const bf16x8*)(wqkvT + ((size_t)(tA2 * 12 + ks + 1) * 64 + lane) * 8);
                #pragma unroll
                for (int mi = 0; mi < 4; ++mi)
                    xfn[mi] = *(const bf16x8*)(xs + XF_ROW(mi) * XS_STRIDE
                                                  + (ks + 1) * 32 + q4 * 8);
            }
            __builtin_amdgcn_s_setprio(1);
            #pragma unroll
            for (int jj = 0; jj < 3; ++jj)
                #pragma unroll
                for (int mi = 0; mi < 4; ++mi)
                    acc[jj][mi] = __builtin_amdgcn_mfma_f32_16x16x32_bf16(
                        wfc[jj], xfc[mi], acc[jj][mi], 0, 0, 0);
            __builtin_amdgcn_s_setprio(0);
            if (ks < 11) {
                #pragma unroll
                for (int jj = 0; jj < 3; ++jj) wfc[jj] = wfn[jj];
                #pragma unroll
                for (int mi = 0; mi < 4; ++mi) xfc[mi] = xfn[mi];
            }
        }
        // epilogue A: (chan=gt*16+q4*4+r, tok=l15) -> q/k arena (swizzled)
        #pragma unroll
        for (int jj = 0; jj < 3; ++jj) {
            const int gt = (jj < 2) ? (2 * wave + jj) : (24 + 2 * wave);
            const int gc = gt * 16 + q4 * 4;
            unsigned char* dstB = (jj < 2) ? aqB : akB;
            const int clb = ((jj < 2) ? (jj * 16 + q4 * 4) : (q4 * 4)) * 2;  // col byte
            float4 bv = *(const float4*)(qkv_b + gc);
            #pragma unroll
            for (int mi = 0; mi < 4; ++mi) {
                const int m = mi * 16 + l15;
                if (m < N_) {
                    bf16x4 o;
                    o[0] = (bf16_t)(acc[jj][mi][0] + bv.x);
                    o[1] = (bf16_t)(acc[jj][mi][1] + bv.y);
                    o[2] = (bf16_t)(acc[jj][mi][2] + bv.z);
                    o[3] = (bf16_t)(acc[jj][mi][3] + bv.w);
                    *(bf16x4*)(dstB + QKSWZ(m, clb)) = o;
                }
            }
        }
    }

    // ---------------- P2 pass 1: {24+2h+1 (A), 48+2h (B), 48+2h+1 (B)} ----
    {
        const int tA = 24 + 2 * wave + 1;
        const int tB0 = 48 + 2 * wave, tB1 = 48 + 2 * wave + 1;
        f32x4 acc[3][4];
        #pragma unroll
        for (int jj = 0; jj < 3; ++jj)
            #pragma unroll
            for (int mi = 0; mi < 4; ++mi) acc[jj][mi] = z4;

        bf16x8 wfc[3], xfc[4];
        wfc[0] = *(const bf16x8*)(wqkvT + ((size_t)(tA * 12) * 64 + lane) * 8);
        wfc[1] = *(const bf16x8*)(wqkvT + ((size_t)(tB0 * 12) * 64 + lane) * 8);
        wfc[2] = *(const bf16x8*)(wqkvT + ((size_t)(tB1 * 12) * 64 + lane) * 8);
        #pragma unroll
        for (int mi = 0; mi < 4; ++mi)
            xfc[mi] = *(const bf16x8*)(xs + XF_ROW(mi) * XS_STRIDE + q4 * 8);

        #pragma unroll
        for (int ks = 0; ks < 12; ++ks) {
            bf16x8 wfn[3], xfn[4];
            if (ks < 11) {
                wfn[0] = *(const bf16x8*)(wqkvT + ((size_t)(tA * 12 + ks + 1) * 64 + lane) * 8);
                wfn[1] = *(const bf16x8*)(wqkvT + ((size_t)(tB0 * 12 + ks + 1) * 64 + lane) * 8);
                wfn[2] = *(const bf16x8*)(wqkvT + ((size_t)(tB1 * 12 + ks + 1) * 64 + lane) * 8);
                #pragma unroll
                for (int mi = 0; mi < 4; ++mi)
                    xfn[mi] = *(const bf16x8*)(xs + XF_ROW(mi) * XS_STRIDE
                                                  + (ks + 1) * 32 + q4 * 8);
            }
            __builtin_amdgcn_s_setprio(1);
            #pragma unroll
            for (int mi = 0; mi < 4; ++mi) {
                acc[0][mi] = __builtin_amdgcn_mfma_f32_16x16x32_bf16(
                    wfc[0], xfc[mi], acc[0][mi], 0, 0, 0);      // A-type (k1)
                acc[1][mi] = __builtin_amdgcn_mfma_f32_16x16x32_bf16(
                    xfc[mi], wfc[1], acc[1][mi], 0, 0, 0);      // B-type (v0)
                acc[2][mi] = __builtin_amdgcn_mfma_f32_16x16x32_bf16(
                    xfc[mi], wfc[2], acc[2][mi], 0, 0, 0);      // B-type (v1)
            }
            __builtin_amdgcn_s_setprio(0);
            if (ks < 11) {
                #pragma unroll
                for (int jj = 0; jj < 3; ++jj) wfc[jj] = wfn[jj];
                #pragma unroll
                for (int mi = 0; mi < 4; ++mi) xfc[mi] = xfn[mi];
            }
        }
        // epilogue A for k1 -> k arena col-byte 32+q4*8 (swizzled)
        {
            const int gc = tA * 16 + q4 * 4;
            float4 bv = *(const float4*)(qkv_b + gc);
            #pragma unroll
            for (int mi = 0; mi < 4; ++mi) {
                const int m = mi * 16 + l15;
                if (m < N_) {
                    bf16x4 o;
                    o[0] = (bf16_t)(acc[0][mi][0] + bv.x);
                    o[1] = (bf16_t)(acc[0][mi][1] + bv.y);
                    o[2] = (bf16_t)(acc[0][mi][2] + bv.z);
                    o[3] = (bf16_t)(acc[0][mi][3] + bv.w);
                    *(bf16x4*)(akB + QKSWZ(m, 32 + q4 * 8)) = o;
                }
            }
        }
        // epilogue B for v0,v1 -> vT arena [dim local][tok]
        #pragma unroll
        for (int jv = 0; jv < 2; ++jv) {
            const int d  = jv * 16 + l15;                       // local dim
            const float bb = qkv_b[(48 + 2 * wave + jv) * 16 + l15];
            #pragma unroll
            for (int mi = 0; mi < 4; ++mi) {
                const int t0 = mi * 16 + q4 * 4;
                if (t0 + 3 < N_) {
                    bf16x4 o;
                    #pragma unroll
                    for (int r = 0; r < 4; ++r) o[r] = (bf16_t)(acc[1 + jv][mi][r] + bb);
                    *(bf16x4*)(av + d * AV_STRIDE + t0) = o;
                } else {
                    #pragma unroll
                    for (int r = 0; r < 4; ++r)
                        if (t0 + r < N_)
                            av[d * AV_STRIDE + t0 + r] = (bf16_t)(acc[1 + jv][mi][r] + bb);
                }
            }
        }
    }
    // NO barrier: wave h's arena is complete; proceed straight to attention.

    // ---------------- P3: attention for head h (private arena) ------------
    {
        bf16_t* pb = ak + 392;   // P at k+784 B (disjoint from ao's k spill)
        const bf16_t* tb = btbl + (size_t)((b & (NW_ - 1)) * H_ + wave) * (N_ * 64);
        const float SC = 0.17677669529663687f * 1.4426950408889634f;

        bf16x8 kf[4];
        #pragma unroll
        for (int ni = 0; ni < 4; ++ni) {
            const int kr = (ni == 3) ? 48 : ni * 16 + l15;
            kf[ni] = *(const bf16x8*)(akB + QKSWZ(kr, q4 * 16));
        }
        bf16x8 vf[2][2];
        #pragma unroll
        for (int ks2 = 0; ks2 < 2; ++ks2)
            #pragma unroll
            for (int dt = 0; dt < 2; ++dt)
                vf[ks2][dt] = *(const bf16x8*)(av + (dt * 16 + l15) * AV_STRIDE
                                                  + ks2 * 32 + q4 * 8);
        bf16x8 qf[4];
        #pragma unroll
        for (int mt = 0; mt < 4; ++mt) {
            const int qr = (mt == 3) ? 48 : mt * 16 + l15;
            qf[mt] = *(const bf16x8*)(aqB + QKSWZ(qr, q4 * 16));
        }
        // q and k fully hoisted; arena repurposed: ao (stride 40) + P.

        #pragma unroll
        for (int mt = 0; mt < 4; ++mt) {
            f32x4 sacc[4];
            __builtin_amdgcn_s_setprio(1);
            #pragma unroll
            for (int ni = 0; ni < 4; ++ni)
                sacc[ni] = __builtin_amdgcn_mfma_f32_16x16x32_bf16(
                    kf[ni], qf[mt], z4, 0, 0, 0);
            __builtin_amdgcn_s_setprio(0);

            const int m  = mt * 16 + l15;
            const int mc = m < 48 ? m : 48;
            float den = 0.f;
            #pragma unroll
            for (int ni = 0; ni < 4; ++ni) {
                bf16x4 bv = *(const bf16x4*)(tb + (size_t)mc * 64 + ni * 16 + q4 * 4);
                #pragma unroll
                for (int r = 0; r < 4; ++r) {
                    const int n = ni * 16 + q4 * 4 + r;
                    float s = 0.f;
                    if (n < N_)
                        s = __builtin_exp2f(sacc[ni][r] * SC + (float)bv[r]);
                    sacc[ni][r] = s;
                    den += s;
                }
            }
            den += __shfl_xor(den, 16);
            den += __shfl_xor(den, 32);
            const float ri = __builtin_amdgcn_rcpf(den);

            // P write (exact zeros for n>=49; rows m>=49 skipped -> stale,
            // masked at ao staging)
            if (m < N_) {
                #pragma unroll
                for (int ni = 0; ni < 4; ++ni) {
                    bf16x4 o;
                    #pragma unroll
                    for (int r = 0; r < 4; ++r) o[r] = (bf16_t)(sacc[ni][r] * ri);
                    *(bf16x4*)(pb + l15 * P_STRIDE + ni * 16 + q4 * 4) = o;
                }
            }

            f32x4 o0 = z4, o1 = z4;
            __builtin_amdgcn_s_setprio(1);
            #pragma unroll
            for (int ks2 = 0; ks2 < 2; ++ks2) {
                bf16x8 pf = *(const bf16x8*)(pb + l15 * P_STRIDE + ks2 * 32 + q4 * 8);
                o0 = __builtin_amdgcn_mfma_f32_16x16x32_bf16(pf, vf[ks2][0], o0, 0, 0, 0);
                o1 = __builtin_amdgcn_mfma_f32_16x16x32_bf16(pf, vf[ks2][1], o1, 0, 0, 0);
            }
            __builtin_amdgcn_s_setprio(0);
            #pragma unroll
            for (int r = 0; r < 4; ++r) {
                const int ms = mt * 16 + q4 * 4 + r;
                if (ms < N_) {
                    aq[ms * AO_STRIDE + l15]      = (bf16_t)o0[r];
                    aq[ms * AO_STRIDE + 16 + l15] = (bf16_t)o1[r];
                }
            }
        }
    }
    __syncthreads();   // B1: all heads' ao staged in arenas

    // ---------------- P4: out = ao @ Wproj + b, 2 col-tiles/wave ----------
    {
        f32x4 pacc[2][4];
        #pragma unroll
        for (int jj = 0; jj < 2; ++jj)
            #pragma unroll
            for (int mi = 0; mi < 4; ++mi) pacc[jj][mi] = z4;

        bf16x8 w0[2], w1[2], afc[4], afn[4];
        #pragma unroll
        for (int jj = 0; jj < 2; ++jj) {
            w0[jj] = *(const bf16x8*)(wprojT +
                ((size_t)((wave * 2 + jj) * 12 + 0) * 64 + lane) * 8);
            w1[jj] = *(const bf16x8*)(wprojT +
                ((size_t)((wave * 2 + jj) * 12 + 1) * 64 + lane) * 8);
        }
        #pragma unroll
        for (int mi = 0; mi < 4; ++mi)
            afc[mi] = *(const bf16x8*)((bf16_t*)(smem + ARENA_OFF)
                                       + XF_ROW(mi) * AO_STRIDE + q4 * 8);

        #pragma unroll
        for (int ks = 0; ks < 12; ++ks) {
            bf16x8 w2[2];
            if (ks < 10) {
                #pragma unroll
                for (int jj = 0; jj < 2; ++jj)
                    w2[jj] = *(const bf16x8*)(wprojT +
                        ((size_t)((wave * 2 + jj) * 12 + ks + 2) * 64 + lane) * 8);
            }
            if (ks < 11) {
                bf16_t* an = (bf16_t*)(smem + ARENA_OFF + (ks + 1) * ARENA_SZ);
                #pragma unroll
                for (int mi = 0; mi < 4; ++mi)
                    afn[mi] = *(const bf16x8*)(an + XF_ROW(mi) * AO_STRIDE + q4 * 8);
            }
            __builtin_amdgcn_s_setprio(1);
            #pragma unroll
            for (int jj = 0; jj < 2; ++jj)
                #pragma unroll
                for (int mi = 0; mi < 4; ++mi)
                    pacc[jj][mi] = __builtin_amdgcn_mfma_f32_16x16x32_bf16(
                        afc[mi], w0[jj], pacc[jj][mi], 0, 0, 0);
            __builtin_amdgcn_s_setprio(0);
            if (ks < 11) {
                #pragma unroll
                for (int jj = 0; jj < 2; ++jj) w0[jj] = w1[jj];
                if (ks < 10) {
                    #pragma unroll
                    for (int jj = 0; jj < 2; ++jj) w1[jj] = w2[jj];
                }
                #pragma unroll
                for (int mi = 0; mi < 4; ++mi) afc[mi] = afn[mi];
            }
        }
        float* og = out + (size_t)b * (N_ * C_);
        #pragma unroll
        for (int jj = 0; jj < 2; ++jj) {
            const int n = (wave * 2 + jj) * 16 + l15;
            const float bias = proj_b[n];
            #pragma unroll
            for (int mi = 0; mi < 4; ++mi) {
                #pragma unroll
                for (int r = 0; r < 4; ++r) {
                    const int m = mi * 16 + q4 * 4 + r;
                    if (m < N_) og[m * C_ + n] = pacc[jj][mi][r] + bias;
                }
            }
        }
    }
}

// ---------------------------------------------------------------------------
extern "C" void kernel_launch(void* const* d_in, const int* in_sizes, int n_in,
                              void* d_out, int out_size, void* d_ws, size_t ws_size,
                              hipStream_t stream)
{
    const float* x      = (const float*)d_in[0];
    const float* mask   = (const float*)d_in[1];
    const float* qkv_w  = (const float*)d_in[2];
    const float* qkv_b  = (const float*)d_in[3];
    const float* proj_w = (const float*)d_in[4];
    const float* proj_b = (const float*)d_in[5];
    const float* rpb    = (const float*)d_in[6];
    float* out = (float*)d_out;

    bf16_t* wqkvT  = (bf16_t*)d_ws;
    bf16_t* wprojT = wqkvT + WQKV_ELEMS;
    bf16_t* btbl   = wprojT + WPROJ_ELEMS;   // 64*12*49*64 bf16 = 4.8 MB

    prep_all<<<288 + NW_ * H_, 256, 0, stream>>>(qkv_w, proj_w, mask, rpb,
                                                 wqkvT, wprojT, btbl);
    fused_window_attn<<<2048, 768, 0, stream>>>(x, qkv_b, proj_b,
                                                wqkvT, wprojT, btbl, out);
}